// Round 6
// baseline (288.456 us; speedup 1.0000x reference)
//
#include <hip/hip_runtime.h>
#include <hip/hip_bf16.h>
#include <math.h>

#define IN_F  1024
#define OUT_F 1024
#define BATCH 8192
#define KD2   7168             // 1024*6 spline (j=2..7; j=0,1 are exact zeros for x in [0,1)) + 1024 silu
#define KCH2  (KD2 / 32)       // 224 chunks of BK=32
#define KCH2H (KCH2 / 2)       // 112 per K-half

typedef short short8  __attribute__((ext_vector_type(8)));
typedef short short4v __attribute__((ext_vector_type(4)));
typedef float f32x4   __attribute__((ext_vector_type(4)));

__device__ __forceinline__ short f2bf(float f) {
    __hip_bfloat16 h = __float2bfloat16(f);   // RNE
    return *reinterpret_cast<short*>(&h);
}

__device__ __forceinline__ float silu(float v) {
    return v / (1.0f + __expf(-v));
}

// 6 bases (j=2..7) for one x in [0,1): 4 nonzero at window offset ci-5 in {0,1,2}.
__device__ __forceinline__ void bases6(float xv, short* __restrict__ o) {
    const float s  = (xv + 2.2f) * 2.5f;     // (x - g0) / h
    const float cf = floorf(s);
    const int  off = (int)cf - 5;            // 0,1,2
    const float u  = s - cf, um = 1.0f - u;
    const float u2 = u * u, u3 = u2 * u, um3 = um * um * um;
    const float k6 = 0.16666667f;
    const float w0 = um3 * k6;
    const float w1 = (3.0f * u3 - 6.0f * u2 + 4.0f) * k6;
    const float w2 = (-3.0f * u3 + 3.0f * u2 + 3.0f * u + 1.0f) * k6;
    const float w3 = u3 * k6;
    o[0] = f2bf(off == 0 ? w0 : 0.0f);
    o[1] = f2bf(off == 0 ? w1 : (off == 1 ? w0 : 0.0f));
    o[2] = f2bf(off == 0 ? w2 : (off == 1 ? w1 : w0));
    o[3] = f2bf(off == 0 ? w3 : (off == 1 ? w2 : w1));
    o[4] = f2bf(off == 1 ? w3 : (off == 2 ? w2 : 0.0f));
    o[5] = f2bf(off == 2 ? w3 : 0.0f);
}

// ===== Phase 1 (merged): A[8192][7168] bf16 and Wt[1024][7168] bf16 =========
// blocks 0..8191: one block per A-row. blocks 8192..9215: one block per Wt-row.
// Both stage the 14336 B row in LDS, then copy out with contiguous 16 B/lane
// stores (the 48 B / 12 B strided direct stores cost 3x write transactions).
__global__ __launch_bounds__(256)
void pack_all(const float* __restrict__ x, const float* __restrict__ base_w,
              const float* __restrict__ spline_w, const float* __restrict__ scaler,
              short* __restrict__ A, short* __restrict__ Wt) {
    __shared__ short buf[KD2];          // 14336 B
    const int b = blockIdx.x;
    const int q = threadIdx.x;          // feature quad 0..255 (4 features)
    short* dstrow;

    if (b < BATCH) {                                   // ---- A row r = b
        const int r = b;
        const float4 xv = *(const float4*)&x[(size_t)r * IN_F + q * 4];
        short t[24];
        bases6(xv.x, t + 0);
        bases6(xv.y, t + 6);
        bases6(xv.z, t + 12);
        bases6(xv.w, t + 18);
        *(short8*)&buf[q * 24 + 0]  = *(short8*)(t + 0);
        *(short8*)&buf[q * 24 + 8]  = *(short8*)(t + 8);
        *(short8*)&buf[q * 24 + 16] = *(short8*)(t + 16);
        short4v sl;
        sl[0] = f2bf(silu(xv.x)); sl[1] = f2bf(silu(xv.y));
        sl[2] = f2bf(silu(xv.z)); sl[3] = f2bf(silu(xv.w));
        *(short4v*)&buf[6144 + q * 4] = sl;
        dstrow = A + (size_t)r * KD2;
    } else {                                           // ---- Wt row o
        const int o = b - BATCH;
        const int i0 = q * 4;
        short t[24];
#pragma unroll
        for (int f = 0; f < 4; ++f) {
            const size_t idx = (size_t)o * IN_F + i0 + f;
            const float sc = scaler[idx];
            const float4* sw4 = (const float4*)(spline_w + idx * 8);
            const float4 w0 = sw4[0], w1 = sw4[1];     // w0: j0..3, w1: j4..7
            t[f * 6 + 0] = f2bf(w0.z * sc);            // j=2
            t[f * 6 + 1] = f2bf(w0.w * sc);            // j=3
            t[f * 6 + 2] = f2bf(w1.x * sc);            // j=4
            t[f * 6 + 3] = f2bf(w1.y * sc);            // j=5
            t[f * 6 + 4] = f2bf(w1.z * sc);            // j=6
            t[f * 6 + 5] = f2bf(w1.w * sc);            // j=7
        }
        *(short8*)&buf[q * 24 + 0]  = *(short8*)(t + 0);
        *(short8*)&buf[q * 24 + 8]  = *(short8*)(t + 8);
        *(short8*)&buf[q * 24 + 16] = *(short8*)(t + 16);
        const float4 bw = *(const float4*)&base_w[(size_t)o * IN_F + i0];
        short4v bv;
        bv[0] = f2bf(bw.x); bv[1] = f2bf(bw.y);
        bv[2] = f2bf(bw.z); bv[3] = f2bf(bw.w);
        *(short4v*)&buf[6144 + q * 4] = bv;
        dstrow = Wt + (size_t)o * KD2;
    }
    __syncthreads();

    // linear copy-out: 3 x (256 thr x 16 B) + 1 x (256 thr x 8 B), coalesced
#pragma unroll
    for (int p = 0; p < 3; ++p)
        *(short8*)&dstrow[p * 2048 + q * 8] = *(short8*)&buf[p * 2048 + q * 8];
    *(short4v*)&dstrow[6144 + q * 4] = *(short4v*)&buf[6144 + q * 4];
}

// ===== Phase 2: split-K=2 GEMM, m97 structure, XCD-swizzled block map =======
#define GLD_LDS16(gp, lp)                                                     \
    __builtin_amdgcn_global_load_lds(                                         \
        (const __attribute__((address_space(1))) unsigned int*)(gp),          \
        (__attribute__((address_space(3))) unsigned int*)(lp), 16, 0, 0)

__global__ __launch_bounds__(256, 4)
void kan_gemm_sk(const short* __restrict__ A, const short* __restrict__ Wt,
                 float* __restrict__ out0, float* __restrict__ out1) {
    __shared__ short As[128 * 32];   // 64 B rows, no pad (gld_lds constraint)
    __shared__ short Bs[128 * 32];

    // All 8 col-blocks of one (row-block, k-half) share lin%8 (= XCD) so the
    // 128-row A-stripe stays in that XCD's L2.
    const int lin = blockIdx.x;          // 0..1023
    const int res = lin & 7;
    const int t   = lin >> 3;            // 0..127
    const int cb  = t & 7;               // col-block 0..7
    const int p   = ((t >> 3) << 3) | res;   // (row-block, k-half) pair 0..127
    const int rb  = p >> 1;
    const int kh  = p & 1;

    const int tid  = threadIdx.x;
    const int lane = tid & 63;
    const int wave = tid >> 6;
    const int row0 = rb * 128;
    const int col0 = cb * 128;
    const int wm0  = (wave & 1) * 64;
    const int wn0  = (wave >> 1) * 64;
    const int lrow = lane & 15;
    const int quad = lane >> 4;

    float* __restrict__ outp = kh ? out1 : out0;

    f32x4 acc[4][4];
#pragma unroll
    for (int i = 0; i < 4; ++i)
#pragma unroll
        for (int j = 0; j < 4; ++j) acc[i][j] = (f32x4)0.0f;

    const int kc0 = kh * KCH2H;
    for (int kc = kc0; kc < kc0 + KCH2H; ++kc) {
#pragma unroll
        for (int t2 = 0; t2 < 2; ++t2) {
            const int e   = (wave * 2 + t2) * 64 + lane;   // 0..511
            const int row = e >> 2, seg = e & 3;           // 4x16B per 64B row
            GLD_LDS16(A  + (size_t)(row0 + row) * KD2 + kc * 32 + seg * 8,
                      As + (wave * 2 + t2) * 512);
            GLD_LDS16(Wt + (size_t)(col0 + row) * KD2 + kc * 32 + seg * 8,
                      Bs + (wave * 2 + t2) * 512);
        }
        __syncthreads();

        short8 a[4], b[4];
#pragma unroll
        for (int i = 0; i < 4; ++i)
            a[i] = *(const short8*)&As[(wm0 + i * 16 + lrow) * 32 + quad * 8];
#pragma unroll
        for (int i = 0; i < 4; ++i)
            b[i] = *(const short8*)&Bs[(wn0 + i * 16 + lrow) * 32 + quad * 8];
#pragma unroll
        for (int i = 0; i < 4; ++i)
#pragma unroll
            for (int j = 0; j < 4; ++j)
                acc[i][j] = __builtin_amdgcn_mfma_f32_16x16x32_bf16(a[i], b[j], acc[i][j], 0, 0, 0);
        __syncthreads();
    }

    // C/D layout: col = lane&15, row = quad*4 + reg  (m89-verified)
#pragma unroll
    for (int i = 0; i < 4; ++i)
#pragma unroll
        for (int j = 0; j < 4; ++j)
#pragma unroll
            for (int r = 0; r < 4; ++r)
                outp[(size_t)(row0 + wm0 + i * 16 + quad * 4 + r) * OUT_F +
                     (col0 + wn0 + j * 16 + lrow)] = acc[i][j][r];
}

// ===== Phase 3: out += partial ==============================================
__global__ __launch_bounds__(256)
void reduce_add(float* __restrict__ out, const float* __restrict__ part) {
    const size_t i = ((size_t)blockIdx.x * 256 + threadIdx.x) * 4;
    float4 a = *(float4*)&out[i];
    const float4 b = *(const float4*)&part[i];
    a.x += b.x; a.y += b.y; a.z += b.z; a.w += b.w;
    *(float4*)&out[i] = a;
}

// ===== Single-K GEMM (middle fallback) ======================================
__global__ __launch_bounds__(256)
void kan_gemm(const short* __restrict__ A, const short* __restrict__ Wt,
              float* __restrict__ out) {
    __shared__ short As[128 * 32];
    __shared__ short Bs[128 * 32];

    const int tid  = threadIdx.x;
    const int lane = tid & 63;
    const int wave = tid >> 6;
    const int row0 = blockIdx.y * 128;
    const int col0 = blockIdx.x * 128;
    const int wm0  = (wave & 1) * 64;
    const int wn0  = (wave >> 1) * 64;
    const int lrow = lane & 15;
    const int quad = lane >> 4;

    f32x4 acc[4][4];
#pragma unroll
    for (int i = 0; i < 4; ++i)
#pragma unroll
        for (int j = 0; j < 4; ++j) acc[i][j] = (f32x4)0.0f;

    for (int kc = 0; kc < KCH2; ++kc) {
#pragma unroll
        for (int t2 = 0; t2 < 2; ++t2) {
            const int e   = (wave * 2 + t2) * 64 + lane;
            const int row = e >> 2, seg = e & 3;
            GLD_LDS16(A  + (size_t)(row0 + row) * KD2 + kc * 32 + seg * 8,
                      As + (wave * 2 + t2) * 512);
            GLD_LDS16(Wt + (size_t)(col0 + row) * KD2 + kc * 32 + seg * 8,
                      Bs + (wave * 2 + t2) * 512);
        }
        __syncthreads();

        short8 a[4], b[4];
#pragma unroll
        for (int i = 0; i < 4; ++i)
            a[i] = *(const short8*)&As[(wm0 + i * 16 + lrow) * 32 + quad * 8];
#pragma unroll
        for (int i = 0; i < 4; ++i)
            b[i] = *(const short8*)&Bs[(wn0 + i * 16 + lrow) * 32 + quad * 8];
#pragma unroll
        for (int i = 0; i < 4; ++i)
#pragma unroll
            for (int j = 0; j < 4; ++j)
                acc[i][j] = __builtin_amdgcn_mfma_f32_16x16x32_bf16(a[i], b[j], acc[i][j], 0, 0, 0);
        __syncthreads();
    }

#pragma unroll
    for (int i = 0; i < 4; ++i)
#pragma unroll
        for (int j = 0; j < 4; ++j)
#pragma unroll
            for (int r = 0; r < 4; ++r)
                out[(size_t)(row0 + wm0 + i * 16 + quad * 4 + r) * OUT_F +
                    (col0 + wn0 + j * 16 + lrow)] = acc[i][j][r];
}

// ===== Fused fallback (no workspace) — round-2 kernel, 8-basis layout =======
#define BM 128
#define BN 128
#define STF 40

__device__ __forceinline__ short8 bases8(float xv) {
    const float s  = (xv + 2.2f) * 2.5f;
    const float cf = floorf(s);
    const int   ci = (int)cf;
    const float u  = s - cf, um = 1.0f - u;
    const float u2 = u * u, u3 = u2 * u, um3 = um * um * um;
    const float k6 = 0.16666667f;
    const float w0 = um3 * k6;
    const float w1 = (3.0f * u3 - 6.0f * u2 + 4.0f) * k6;
    const float w2 = (-3.0f * u3 + 3.0f * u2 + 3.0f * u + 1.0f) * k6;
    const float w3 = u3 * k6;
    short8 o;
#pragma unroll
    for (int j = 0; j < 8; ++j) {
        const float v5 = (j == 2) ? w0 : (j == 3) ? w1 : (j == 4) ? w2 : (j == 5) ? w3 : 0.0f;
        const float v6 = (j == 3) ? w0 : (j == 4) ? w1 : (j == 5) ? w2 : (j == 6) ? w3 : 0.0f;
        const float v7 = (j == 4) ? w0 : (j == 5) ? w1 : (j == 6) ? w2 : (j == 7) ? w3 : 0.0f;
        o[j] = f2bf((ci == 5) ? v5 : (ci == 6) ? v6 : v7);
    }
    return o;
}

__global__ __launch_bounds__(256)
void kan_mfma(const float* __restrict__ x,
              const float* __restrict__ base_w,
              const float* __restrict__ spline_w,
              const float* __restrict__ scaler,
              float* __restrict__ out) {
    __shared__ short As[BM * STF];
    __shared__ short Bs[BN * STF];

    const int tid  = threadIdx.x;
    const int lane = tid & 63;
    const int wave = tid >> 6;
    const int row0 = blockIdx.y * BM;
    const int col0 = blockIdx.x * BN;
    const int wm0  = (wave & 1) * 64;
    const int wn0  = (wave >> 1) * 64;
    const int lrow = lane & 15;
    const int quad = lane >> 4;

    f32x4 acc[4][4];
#pragma unroll
    for (int i = 0; i < 4; ++i)
#pragma unroll
        for (int j = 0; j < 4; ++j) acc[i][j] = (f32x4)0.0f;

    for (int kc = 0; kc < 256; ++kc) {
        const int fi0 = kc * 4;
#pragma unroll
        for (int it = 0; it < 2; ++it) {
            const int e = tid + it * 256;
            const int r = e >> 2, f = e & 3;
            const float xv = x[(size_t)(row0 + r) * IN_F + fi0 + f];
            *(short8*)&As[r * STF + f * 8] = bases8(xv);
        }
#pragma unroll
        for (int it = 0; it < 4; ++it) {
            const int idx = tid + it * 256;
            const int c = idx >> 3, q = idx & 7;
            const int f = q >> 1;
            const size_t base = ((size_t)(col0 + c) * IN_F + fi0 + f) * 8 + (size_t)(q & 1) * 4;
            const float4 w = *(const float4*)&spline_w[base];
            const float sc = scaler[(size_t)(col0 + c) * IN_F + fi0 + f];
            short4v o;
            o[0] = f2bf(w.x * sc); o[1] = f2bf(w.y * sc);
            o[2] = f2bf(w.z * sc); o[3] = f2bf(w.w * sc);
            *(short4v*)&Bs[c * STF + q * 4] = o;
        }
        __syncthreads();
        short8 a[4], b[4];
#pragma unroll
        for (int i = 0; i < 4; ++i)
            a[i] = *(const short8*)&As[(wm0 + i * 16 + lrow) * STF + quad * 8];
#pragma unroll
        for (int i = 0; i < 4; ++i)
            b[i] = *(const short8*)&Bs[(wn0 + i * 16 + lrow) * STF + quad * 8];
#pragma unroll
        for (int i = 0; i < 4; ++i)
#pragma unroll
            for (int j = 0; j < 4; ++j)
                acc[i][j] = __builtin_amdgcn_mfma_f32_16x16x32_bf16(a[i], b[j], acc[i][j], 0, 0, 0);
        __syncthreads();
    }

    for (int sc = 0; sc < 32; ++sc) {
        const int fi0 = sc * 32;
#pragma unroll
        for (int it = 0; it < 4; ++it) {
            const int idx = tid + it * 256;
            const int r = idx >> 3, q = idx & 7;
            const float4 xv = *(const float4*)&x[(size_t)(row0 + r) * IN_F + fi0 + q * 4];
            short4v o;
            o[0] = f2bf(silu(xv.x)); o[1] = f2bf(silu(xv.y));
            o[2] = f2bf(silu(xv.z)); o[3] = f2bf(silu(xv.w));
            *(short4v*)&As[r * STF + q * 4] = o;
        }
#pragma unroll
        for (int it = 0; it < 4; ++it) {
            const int idx = tid + it * 256;
            const int c = idx >> 3, q = idx & 7;
            const float4 wv = *(const float4*)&base_w[(size_t)(col0 + c) * IN_F + fi0 + q * 4];
            short4v o;
            o[0] = f2bf(wv.x); o[1] = f2bf(wv.y);
            o[2] = f2bf(wv.z); o[3] = f2bf(wv.w);
            *(short4v*)&Bs[c * STF + q * 4] = o;
        }
        __syncthreads();
        short8 a[4], b[4];
#pragma unroll
        for (int i = 0; i < 4; ++i)
            a[i] = *(const short8*)&As[(wm0 + i * 16 + lrow) * STF + quad * 8];
#pragma unroll
        for (int i = 0; i < 4; ++i)
            b[i] = *(const short8*)&Bs[(wn0 + i * 16 + lrow) * STF + quad * 8];
#pragma unroll
        for (int i = 0; i < 4; ++i)
#pragma unroll
            for (int j = 0; j < 4; ++j)
                acc[i][j] = __builtin_amdgcn_mfma_f32_16x16x32_bf16(a[i], b[j], acc[i][j], 0, 0, 0);
        __syncthreads();
    }

#pragma unroll
    for (int i = 0; i < 4; ++i)
#pragma unroll
        for (int j = 0; j < 4; ++j)
#pragma unroll
            for (int r = 0; r < 4; ++r)
                out[(size_t)(row0 + wm0 + i * 16 + quad * 4 + r) * OUT_F +
                    (col0 + wn0 + j * 16 + lrow)] = acc[i][j][r];
}

extern "C" void kernel_launch(void* const* d_in, const int* in_sizes, int n_in,
                              void* d_out, int out_size, void* d_ws, size_t ws_size,
                              hipStream_t stream) {
    const float* x        = (const float*)d_in[0];
    const float* base_w   = (const float*)d_in[1];
    const float* spline_w = (const float*)d_in[2];
    const float* scaler   = (const float*)d_in[3];
    float* out = (float*)d_out;

    const size_t need_A = (size_t)BATCH * KD2 * sizeof(short);   // 117.4 MB
    const size_t need_W = (size_t)OUT_F * KD2 * sizeof(short);   //  14.7 MB
    const size_t need_P = (size_t)BATCH * OUT_F * sizeof(float); //  33.6 MB

    if (ws_size >= need_A + need_W + need_P) {
        short* A  = (short*)d_ws;
        short* Wt = (short*)((char*)d_ws + need_A);
        float* P  = (float*)((char*)d_ws + need_A + need_W);
        pack_all<<<BATCH + OUT_F, 256, 0, stream>>>(x, base_w, spline_w, scaler, A, Wt);
        kan_gemm_sk<<<1024, 256, 0, stream>>>(A, Wt, out, P);
        reduce_add<<<BATCH * OUT_F / 1024, 256, 0, stream>>>(out, P);
    } else if (ws_size >= need_A + need_W) {
        short* A  = (short*)d_ws;
        short* Wt = (short*)((char*)d_ws + need_A);
        pack_all<<<BATCH + OUT_F, 256, 0, stream>>>(x, base_w, spline_w, scaler, A, Wt);
        dim3 grd(OUT_F / 128, BATCH / 128);
        kan_gemm<<<grd, 256, 0, stream>>>(A, Wt, out);
    } else {
        dim3 grd(OUT_F / BN, BATCH / BM);
        kan_mfma<<<grd, 256, 0, stream>>>(x, base_w, spline_w, scaler, out);
    }
}

// Round 7
// 279.707 us; speedup vs baseline: 1.0313x; 1.0313x over previous
//
#include <hip/hip_runtime.h>
#include <hip/hip_bf16.h>
#include <math.h>

#define IN_F  1024
#define OUT_F 1024
#define BATCH 8192
#define KD2   7168             // 1024*6 spline (j=2..7; j=0,1 are exact zeros for x in [0,1)) + 1024 silu
#define KCH2  (KD2 / 32)       // 224 chunks of BK=32
#define KCH2H (KCH2 / 2)       // 112 per K-half (56 double-chunks)

typedef short short8  __attribute__((ext_vector_type(8)));
typedef short short4v __attribute__((ext_vector_type(4)));
typedef float f32x4   __attribute__((ext_vector_type(4)));

__device__ __forceinline__ short f2bf(float f) {
    __hip_bfloat16 h = __float2bfloat16(f);   // RNE
    return *reinterpret_cast<short*>(&h);
}

__device__ __forceinline__ float silu(float v) {
    return v / (1.0f + __expf(-v));
}

// 6 bases (j=2..7) for one x in [0,1): 4 nonzero at window offset ci-5 in {0,1,2}.
__device__ __forceinline__ void bases6(float xv, short* __restrict__ o) {
    const float s  = (xv + 2.2f) * 2.5f;     // (x - g0) / h
    const float cf = floorf(s);
    const int  off = (int)cf - 5;            // 0,1,2
    const float u  = s - cf, um = 1.0f - u;
    const float u2 = u * u, u3 = u2 * u, um3 = um * um * um;
    const float k6 = 0.16666667f;
    const float w0 = um3 * k6;
    const float w1 = (3.0f * u3 - 6.0f * u2 + 4.0f) * k6;
    const float w2 = (-3.0f * u3 + 3.0f * u2 + 3.0f * u + 1.0f) * k6;
    const float w3 = u3 * k6;
    o[0] = f2bf(off == 0 ? w0 : 0.0f);
    o[1] = f2bf(off == 0 ? w1 : (off == 1 ? w0 : 0.0f));
    o[2] = f2bf(off == 0 ? w2 : (off == 1 ? w1 : w0));
    o[3] = f2bf(off == 0 ? w3 : (off == 1 ? w2 : w1));
    o[4] = f2bf(off == 1 ? w3 : (off == 2 ? w2 : 0.0f));
    o[5] = f2bf(off == 2 ? w3 : 0.0f);
}

// ===== Phase 1 (merged): A[8192][7168] bf16 and Wt[1024][7168] bf16 =========
__global__ __launch_bounds__(256)
void pack_all(const float* __restrict__ x, const float* __restrict__ base_w,
              const float* __restrict__ spline_w, const float* __restrict__ scaler,
              short* __restrict__ A, short* __restrict__ Wt) {
    __shared__ short buf[KD2];          // 14336 B
    const int b = blockIdx.x;
    const int q = threadIdx.x;          // feature quad 0..255 (4 features)
    short* dstrow;

    if (b < BATCH) {                                   // ---- A row r = b
        const int r = b;
        const float4 xv = *(const float4*)&x[(size_t)r * IN_F + q * 4];
        short t[24];
        bases6(xv.x, t + 0);
        bases6(xv.y, t + 6);
        bases6(xv.z, t + 12);
        bases6(xv.w, t + 18);
        *(short8*)&buf[q * 24 + 0]  = *(short8*)(t + 0);
        *(short8*)&buf[q * 24 + 8]  = *(short8*)(t + 8);
        *(short8*)&buf[q * 24 + 16] = *(short8*)(t + 16);
        short4v sl;
        sl[0] = f2bf(silu(xv.x)); sl[1] = f2bf(silu(xv.y));
        sl[2] = f2bf(silu(xv.z)); sl[3] = f2bf(silu(xv.w));
        *(short4v*)&buf[6144 + q * 4] = sl;
        dstrow = A + (size_t)r * KD2;
    } else {                                           // ---- Wt row o
        const int o = b - BATCH;
        const int i0 = q * 4;
        short t[24];
#pragma unroll
        for (int f = 0; f < 4; ++f) {
            const size_t idx = (size_t)o * IN_F + i0 + f;
            const float sc = scaler[idx];
            const float4* sw4 = (const float4*)(spline_w + idx * 8);
            const float4 w0 = sw4[0], w1 = sw4[1];     // w0: j0..3, w1: j4..7
            t[f * 6 + 0] = f2bf(w0.z * sc);            // j=2
            t[f * 6 + 1] = f2bf(w0.w * sc);            // j=3
            t[f * 6 + 2] = f2bf(w1.x * sc);            // j=4
            t[f * 6 + 3] = f2bf(w1.y * sc);            // j=5
            t[f * 6 + 4] = f2bf(w1.z * sc);            // j=6
            t[f * 6 + 5] = f2bf(w1.w * sc);            // j=7
        }
        *(short8*)&buf[q * 24 + 0]  = *(short8*)(t + 0);
        *(short8*)&buf[q * 24 + 8]  = *(short8*)(t + 8);
        *(short8*)&buf[q * 24 + 16] = *(short8*)(t + 16);
        const float4 bw = *(const float4*)&base_w[(size_t)o * IN_F + i0];
        short4v bv;
        bv[0] = f2bf(bw.x); bv[1] = f2bf(bw.y);
        bv[2] = f2bf(bw.z); bv[3] = f2bf(bw.w);
        *(short4v*)&buf[6144 + q * 4] = bv;
        dstrow = Wt + (size_t)o * KD2;
    }
    __syncthreads();

#pragma unroll
    for (int p = 0; p < 3; ++p)
        *(short8*)&dstrow[p * 2048 + q * 8] = *(short8*)&buf[p * 2048 + q * 8];
    *(short4v*)&dstrow[6144 + q * 4] = *(short4v*)&buf[6144 + q * 4];
}

// ===== Phase 2: split-K=2 GEMM, 2 chunks/barrier (32 MFMA per barrier) ======
#define GLD_LDS16(gp, lp)                                                     \
    __builtin_amdgcn_global_load_lds(                                         \
        (const __attribute__((address_space(1))) unsigned int*)(gp),          \
        (__attribute__((address_space(3))) unsigned int*)(lp), 16, 0, 0)

__global__ __launch_bounds__(256, 4)
void kan_gemm_sk(const short* __restrict__ A, const short* __restrict__ Wt,
                 float* __restrict__ out0, float* __restrict__ out1) {
    // Two chunk-buffers per matrix: 4 x 8 KB = 32 KB total -> 4 blocks/CU.
    __shared__ short As[2][128 * 32];   // 64 B rows, no pad (gld_lds constraint)
    __shared__ short Bs[2][128 * 32];

    // All 8 col-blocks of one (row-block, k-half) share lin%8 (= XCD) so the
    // 128-row A-stripe stays in that XCD's L2.
    const int lin = blockIdx.x;          // 0..1023
    const int res = lin & 7;
    const int t   = lin >> 3;            // 0..127
    const int cb  = t & 7;               // col-block 0..7
    const int p   = ((t >> 3) << 3) | res;   // (row-block, k-half) pair 0..127
    const int rb  = p >> 1;
    const int kh  = p & 1;

    const int tid  = threadIdx.x;
    const int lane = tid & 63;
    const int wave = tid >> 6;
    const int row0 = rb * 128;
    const int col0 = cb * 128;
    const int wm0  = (wave & 1) * 64;
    const int wn0  = (wave >> 1) * 64;
    const int lrow = lane & 15;
    const int quad = lane >> 4;

    float* __restrict__ outp = kh ? out1 : out0;

    f32x4 acc[4][4];
#pragma unroll
    for (int i = 0; i < 4; ++i)
#pragma unroll
        for (int j = 0; j < 4; ++j) acc[i][j] = (f32x4)0.0f;

    // staging lane geometry (per 32-k chunk): 512 segs of 16 B, 2 insts/wave
    const int e0  = wave * 2 * 64 + lane;         // t2=0
    const int e1  = e0 + 64;                      // t2=1
    const int r0s = e0 >> 2, s0 = e0 & 3;
    const int r1s = e1 >> 2, s1 = e1 & 3;

    const int kc0 = kh * KCH2H;
    for (int kc = kc0; kc < kc0 + KCH2H; kc += 2) {
#pragma unroll
        for (int d = 0; d < 2; ++d) {             // double-chunk: kc+d -> buf d
            const int kk = (kc + d) * 32;
            GLD_LDS16(A  + (size_t)(row0 + r0s) * KD2 + kk + s0 * 8,
                      &As[d][wave * 2 * 512]);
            GLD_LDS16(Wt + (size_t)(col0 + r0s) * KD2 + kk + s0 * 8,
                      &Bs[d][wave * 2 * 512]);
            GLD_LDS16(A  + (size_t)(row0 + r1s) * KD2 + kk + s1 * 8,
                      &As[d][(wave * 2 + 1) * 512]);
            GLD_LDS16(Wt + (size_t)(col0 + r1s) * KD2 + kk + s1 * 8,
                      &Bs[d][(wave * 2 + 1) * 512]);
        }
        __syncthreads();

#pragma unroll
        for (int d = 0; d < 2; ++d) {             // 32 MFMA between barriers
            short8 a[4], b[4];
#pragma unroll
            for (int i = 0; i < 4; ++i)
                a[i] = *(const short8*)&As[d][(wm0 + i * 16 + lrow) * 32 + quad * 8];
#pragma unroll
            for (int i = 0; i < 4; ++i)
                b[i] = *(const short8*)&Bs[d][(wn0 + i * 16 + lrow) * 32 + quad * 8];
#pragma unroll
            for (int i = 0; i < 4; ++i)
#pragma unroll
                for (int j = 0; j < 4; ++j)
                    acc[i][j] = __builtin_amdgcn_mfma_f32_16x16x32_bf16(a[i], b[j], acc[i][j], 0, 0, 0);
        }
        __syncthreads();
    }

    // C/D layout: col = lane&15, row = quad*4 + reg  (m89-verified)
#pragma unroll
    for (int i = 0; i < 4; ++i)
#pragma unroll
        for (int j = 0; j < 4; ++j)
#pragma unroll
            for (int r = 0; r < 4; ++r)
                outp[(size_t)(row0 + wm0 + i * 16 + quad * 4 + r) * OUT_F +
                     (col0 + wn0 + j * 16 + lrow)] = acc[i][j][r];
}

// ===== Phase 3: out += partial ==============================================
__global__ __launch_bounds__(256)
void reduce_add(float* __restrict__ out, const float* __restrict__ part) {
    const size_t i = ((size_t)blockIdx.x * 256 + threadIdx.x) * 4;
    float4 a = *(float4*)&out[i];
    const float4 b = *(const float4*)&part[i];
    a.x += b.x; a.y += b.y; a.z += b.z; a.w += b.w;
    *(float4*)&out[i] = a;
}

// ===== Single-K GEMM (middle fallback), same double-chunk structure =========
__global__ __launch_bounds__(256, 4)
void kan_gemm(const short* __restrict__ A, const short* __restrict__ Wt,
              float* __restrict__ out) {
    __shared__ short As[2][128 * 32];
    __shared__ short Bs[2][128 * 32];

    const int tid  = threadIdx.x;
    const int lane = tid & 63;
    const int wave = tid >> 6;
    const int row0 = blockIdx.y * 128;
    const int col0 = blockIdx.x * 128;
    const int wm0  = (wave & 1) * 64;
    const int wn0  = (wave >> 1) * 64;
    const int lrow = lane & 15;
    const int quad = lane >> 4;

    f32x4 acc[4][4];
#pragma unroll
    for (int i = 0; i < 4; ++i)
#pragma unroll
        for (int j = 0; j < 4; ++j) acc[i][j] = (f32x4)0.0f;

    const int e0  = wave * 2 * 64 + lane;
    const int e1  = e0 + 64;
    const int r0s = e0 >> 2, s0 = e0 & 3;
    const int r1s = e1 >> 2, s1 = e1 & 3;

    for (int kc = 0; kc < KCH2; kc += 2) {
#pragma unroll
        for (int d = 0; d < 2; ++d) {
            const int kk = (kc + d) * 32;
            GLD_LDS16(A  + (size_t)(row0 + r0s) * KD2 + kk + s0 * 8,
                      &As[d][wave * 2 * 512]);
            GLD_LDS16(Wt + (size_t)(col0 + r0s) * KD2 + kk + s0 * 8,
                      &Bs[d][wave * 2 * 512]);
            GLD_LDS16(A  + (size_t)(row0 + r1s) * KD2 + kk + s1 * 8,
                      &As[d][(wave * 2 + 1) * 512]);
            GLD_LDS16(Wt + (size_t)(col0 + r1s) * KD2 + kk + s1 * 8,
                      &Bs[d][(wave * 2 + 1) * 512]);
        }
        __syncthreads();

#pragma unroll
        for (int d = 0; d < 2; ++d) {
            short8 a[4], b[4];
#pragma unroll
            for (int i = 0; i < 4; ++i)
                a[i] = *(const short8*)&As[d][(wm0 + i * 16 + lrow) * 32 + quad * 8];
#pragma unroll
            for (int i = 0; i < 4; ++i)
                b[i] = *(const short8*)&Bs[d][(wn0 + i * 16 + lrow) * 32 + quad * 8];
#pragma unroll
            for (int i = 0; i < 4; ++i)
#pragma unroll
                for (int j = 0; j < 4; ++j)
                    acc[i][j] = __builtin_amdgcn_mfma_f32_16x16x32_bf16(a[i], b[j], acc[i][j], 0, 0, 0);
        }
        __syncthreads();
    }

#pragma unroll
    for (int i = 0; i < 4; ++i)
#pragma unroll
        for (int j = 0; j < 4; ++j)
#pragma unroll
            for (int r = 0; r < 4; ++r)
                out[(size_t)(row0 + wm0 + i * 16 + quad * 4 + r) * OUT_F +
                    (col0 + wn0 + j * 16 + lrow)] = acc[i][j][r];
}

// ===== Fused fallback (no workspace) — round-2 kernel, 8-basis layout =======
#define BM 128
#define BN 128
#define STF 40

__device__ __forceinline__ short8 bases8(float xv) {
    const float s  = (xv + 2.2f) * 2.5f;
    const float cf = floorf(s);
    const int   ci = (int)cf;
    const float u  = s - cf, um = 1.0f - u;
    const float u2 = u * u, u3 = u2 * u, um3 = um * um * um;
    const float k6 = 0.16666667f;
    const float w0 = um3 * k6;
    const float w1 = (3.0f * u3 - 6.0f * u2 + 4.0f) * k6;
    const float w2 = (-3.0f * u3 + 3.0f * u2 + 3.0f * u + 1.0f) * k6;
    const float w3 = u3 * k6;
    short8 o;
#pragma unroll
    for (int j = 0; j < 8; ++j) {
        const float v5 = (j == 2) ? w0 : (j == 3) ? w1 : (j == 4) ? w2 : (j == 5) ? w3 : 0.0f;
        const float v6 = (j == 3) ? w0 : (j == 4) ? w1 : (j == 5) ? w2 : (j == 6) ? w3 : 0.0f;
        const float v7 = (j == 4) ? w0 : (j == 5) ? w1 : (j == 6) ? w2 : (j == 7) ? w3 : 0.0f;
        o[j] = f2bf((ci == 5) ? v5 : (ci == 6) ? v6 : v7);
    }
    return o;
}

__global__ __launch_bounds__(256)
void kan_mfma(const float* __restrict__ x,
              const float* __restrict__ base_w,
              const float* __restrict__ spline_w,
              const float* __restrict__ scaler,
              float* __restrict__ out) {
    __shared__ short As[BM * STF];
    __shared__ short Bs[BN * STF];

    const int tid  = threadIdx.x;
    const int lane = tid & 63;
    const int wave = tid >> 6;
    const int row0 = blockIdx.y * BM;
    const int col0 = blockIdx.x * BN;
    const int wm0  = (wave & 1) * 64;
    const int wn0  = (wave >> 1) * 64;
    const int lrow = lane & 15;
    const int quad = lane >> 4;

    f32x4 acc[4][4];
#pragma unroll
    for (int i = 0; i < 4; ++i)
#pragma unroll
        for (int j = 0; j < 4; ++j) acc[i][j] = (f32x4)0.0f;

    for (int kc = 0; kc < 256; ++kc) {
        const int fi0 = kc * 4;
#pragma unroll
        for (int it = 0; it < 2; ++it) {
            const int e = tid + it * 256;
            const int r = e >> 2, f = e & 3;
            const float xv = x[(size_t)(row0 + r) * IN_F + fi0 + f];
            *(short8*)&As[r * STF + f * 8] = bases8(xv);
        }
#pragma unroll
        for (int it = 0; it < 4; ++it) {
            const int idx = tid + it * 256;
            const int c = idx >> 3, q = idx & 7;
            const int f = q >> 1;
            const size_t base = ((size_t)(col0 + c) * IN_F + fi0 + f) * 8 + (size_t)(q & 1) * 4;
            const float4 w = *(const float4*)&spline_w[base];
            const float sc = scaler[(size_t)(col0 + c) * IN_F + fi0 + f];
            short4v o;
            o[0] = f2bf(w.x * sc); o[1] = f2bf(w.y * sc);
            o[2] = f2bf(w.z * sc); o[3] = f2bf(w.w * sc);
            *(short4v*)&Bs[c * STF + q * 4] = o;
        }
        __syncthreads();
        short8 a[4], b[4];
#pragma unroll
        for (int i = 0; i < 4; ++i)
            a[i] = *(const short8*)&As[(wm0 + i * 16 + lrow) * STF + quad * 8];
#pragma unroll
        for (int i = 0; i < 4; ++i)
            b[i] = *(const short8*)&Bs[(wn0 + i * 16 + lrow) * STF + quad * 8];
#pragma unroll
        for (int i = 0; i < 4; ++i)
#pragma unroll
            for (int j = 0; j < 4; ++j)
                acc[i][j] = __builtin_amdgcn_mfma_f32_16x16x32_bf16(a[i], b[j], acc[i][j], 0, 0, 0);
        __syncthreads();
    }

    for (int sc = 0; sc < 32; ++sc) {
        const int fi0 = sc * 32;
#pragma unroll
        for (int it = 0; it < 4; ++it) {
            const int idx = tid + it * 256;
            const int r = idx >> 3, q = idx & 7;
            const float4 xv = *(const float4*)&x[(size_t)(row0 + r) * IN_F + fi0 + q * 4];
            short4v o;
            o[0] = f2bf(silu(xv.x)); o[1] = f2bf(silu(xv.y));
            o[2] = f2bf(silu(xv.z)); o[3] = f2bf(silu(xv.w));
            *(short4v*)&As[r * STF + q * 4] = o;
        }
#pragma unroll
        for (int it = 0; it < 4; ++it) {
            const int idx = tid + it * 256;
            const int c = idx >> 3, q = idx & 7;
            const float4 wv = *(const float4*)&base_w[(size_t)(col0 + c) * IN_F + fi0 + q * 4];
            short4v o;
            o[0] = f2bf(wv.x); o[1] = f2bf(wv.y);
            o[2] = f2bf(wv.z); o[3] = f2bf(wv.w);
            *(short4v*)&Bs[c * STF + q * 4] = o;
        }
        __syncthreads();
        short8 a[4], b[4];
#pragma unroll
        for (int i = 0; i < 4; ++i)
            a[i] = *(const short8*)&As[(wm0 + i * 16 + lrow) * STF + quad * 8];
#pragma unroll
        for (int i = 0; i < 4; ++i)
            b[i] = *(const short8*)&Bs[(wn0 + i * 16 + lrow) * STF + quad * 8];
#pragma unroll
        for (int i = 0; i < 4; ++i)
#pragma unroll
            for (int j = 0; j < 4; ++j)
                acc[i][j] = __builtin_amdgcn_mfma_f32_16x16x32_bf16(a[i], b[j], acc[i][j], 0, 0, 0);
        __syncthreads();
    }

#pragma unroll
    for (int i = 0; i < 4; ++i)
#pragma unroll
        for (int j = 0; j < 4; ++j)
#pragma unroll
            for (int r = 0; r < 4; ++r)
                out[(size_t)(row0 + wm0 + i * 16 + quad * 4 + r) * OUT_F +
                    (col0 + wn0 + j * 16 + lrow)] = acc[i][j][r];
}

extern "C" void kernel_launch(void* const* d_in, const int* in_sizes, int n_in,
                              void* d_out, int out_size, void* d_ws, size_t ws_size,
                              hipStream_t stream) {
    const float* x        = (const float*)d_in[0];
    const float* base_w   = (const float*)d_in[1];
    const float* spline_w = (const float*)d_in[2];
    const float* scaler   = (const float*)d_in[3];
    float* out = (float*)d_out;

    const size_t need_A = (size_t)BATCH * KD2 * sizeof(short);   // 117.4 MB
    const size_t need_W = (size_t)OUT_F * KD2 * sizeof(short);   //  14.7 MB
    const size_t need_P = (size_t)BATCH * OUT_F * sizeof(float); //  33.6 MB

    if (ws_size >= need_A + need_W + need_P) {
        short* A  = (short*)d_ws;
        short* Wt = (short*)((char*)d_ws + need_A);
        float* P  = (float*)((char*)d_ws + need_A + need_W);
        pack_all<<<BATCH + OUT_F, 256, 0, stream>>>(x, base_w, spline_w, scaler, A, Wt);
        kan_gemm_sk<<<1024, 256, 0, stream>>>(A, Wt, out, P);
        reduce_add<<<BATCH * OUT_F / 1024, 256, 0, stream>>>(out, P);
    } else if (ws_size >= need_A + need_W) {
        short* A  = (short*)d_ws;
        short* Wt = (short*)((char*)d_ws + need_A);
        pack_all<<<BATCH + OUT_F, 256, 0, stream>>>(x, base_w, spline_w, scaler, A, Wt);
        dim3 grd(OUT_F / 128, BATCH / 128);
        kan_gemm<<<grd, 256, 0, stream>>>(A, Wt, out);
    } else {
        dim3 grd(OUT_F / BN, BATCH / BM);
        kan_mfma<<<grd, 256, 0, stream>>>(x, base_w, spline_w, scaler, out);
    }
}